// Round 5
// baseline (53.660 us; speedup 1.0000x reference)
//
#include <hip/hip_runtime.h>
#include <hip/hip_bf16.h>

#define N_      2048
#define TWO_N   4096
#define DFEAT   128
#define SCALE   2.0f                   // 1 / TEMPERATURE
#define CCHUNKS 32                     // column chunks in k_simsum
#define CCOLS   (TWO_N / CCHUNKS)      // 128
#define NT      (CCOLS / 16)           // 8 column-tiles per chunk
#define GRID_X  (TWO_N / 64)           // 64 row strips

typedef __attribute__((ext_vector_type(8))) short bf16x8;
typedef __attribute__((ext_vector_type(4))) float f32x4;

// ---------------------------------------------------------------------------
// Kernel 1 (fused prep), 1024 blocks x 256 thr (4 waves = 4 rows per block):
//   row < N : normalize anchor row -> zn16[row], AND dvec[row] = 2*cos(a,neg)
//   row >= N: normalize pos row   -> zn16[row]
//   Also zero-inits the atomic accumulators accS[4096] / accP[2048]
//   (stream order makes these visible to k_simsum; no memset dispatch).
// ---------------------------------------------------------------------------
__global__ __launch_bounds__(256) void k_prep(const float* __restrict__ a,
                                              const float* __restrict__ p,
                                              const float* __restrict__ ng,
                                              __hip_bfloat16* __restrict__ zn16,
                                              float* __restrict__ dvec,
                                              float* __restrict__ accS,
                                              float* __restrict__ accP) {
  const int wave = threadIdx.x >> 6;
  const int lane = threadIdx.x & 63;
  const int row  = blockIdx.x * 4 + wave;   // 0..4095

  // zero atomic accumulators: 4 accS + 2 accP entries per block
  if (threadIdx.x < 4)        accS[blockIdx.x * 4 + threadIdx.x] = 0.0f;
  else if (threadIdx.x < 6)   accP[blockIdx.x * 2 + threadIdx.x - 4] = 0.0f;

  if (row < N_) {
    float2 u = ((const float2*)(a  + (size_t)row * DFEAT))[lane];
    float2 w = ((const float2*)(ng + (size_t)row * DFEAT))[lane];
    float saa = u.x * u.x + u.y * u.y;
    float snn = w.x * w.x + w.y * w.y;
    float san = u.x * w.x + u.y * w.y;
#pragma unroll
    for (int m = 1; m < 64; m <<= 1) {
      saa += __shfl_xor(saa, m);
      snn += __shfl_xor(snn, m);
      san += __shfl_xor(san, m);
    }
    float na = fmaxf(sqrtf(saa), 1e-8f);
    float rn = 1.0f / na;
    __hip_bfloat162 h;
    h.x = __float2bfloat16(u.x * rn);
    h.y = __float2bfloat16(u.y * rn);
    ((__hip_bfloat162*)zn16)[row * (DFEAT / 2) + lane] = h;
    if (lane == 0)
      dvec[row] = SCALE * san / (na * fmaxf(sqrtf(snn), 1e-8f));
  } else {
    float2 v = ((const float2*)(p + (size_t)(row - N_) * DFEAT))[lane];
    float ss = v.x * v.x + v.y * v.y;
#pragma unroll
    for (int m = 1; m < 64; m <<= 1) ss += __shfl_xor(ss, m);
    float rn = 1.0f / fmaxf(sqrtf(ss), 1e-8f);
    __hip_bfloat162 h;
    h.x = __float2bfloat16(v.x * rn);
    h.y = __float2bfloat16(v.y * rn);
    ((__hip_bfloat162*)zn16)[row * (DFEAT / 2) + lane] = h;
  }
}

// ---------------------------------------------------------------------------
// Kernel 2: fused G = zn@zn^T /T, exp, masked row-segment sums -> atomics.
//   grid = (64 row strips, 32 col chunks) = 2048 blocks, 256 thr (4 waves).
//   8 blocks/CU = 32 waves/CU (launch_bounds(256,8) keeps VGPR <= 64).
//   Each wave: 16-row strip, NT=8 col tiles, MFMA 16x16x32 bf16 over K=128
//   (two independent 2-deep accumulator chains).
//   accS[r]  += sum of exp over this chunk's cols (masked)
//   accP[r-N]+= prefix part (cols < r-N) for hi rows
// ---------------------------------------------------------------------------
__global__ __launch_bounds__(256, 8) void k_simsum(const __hip_bfloat16* __restrict__ zn16,
                                                   float* __restrict__ accS,
                                                   float* __restrict__ accP) {
  const int wave = threadIdx.x >> 6;
  const int lane = threadIdx.x & 63;
  const int lr   = lane & 15;   // A-row / B-col within tile
  const int kg   = lane >> 4;   // k-group
  const int rows_base = blockIdx.x * 64 + wave * 16;
  const int cb0 = blockIdx.y * CCOLS;
  const short* zs = (const short*)zn16;

  // A fragments for this wave's 16 rows, all K=128 (4 subtiles), in regs
  bf16x8 a[4];
#pragma unroll
  for (int kk = 0; kk < 4; ++kk)
    a[kk] = *(const bf16x8*)(zs + (size_t)(rows_base + lr) * DFEAT + kk * 32 + kg * 8);

  const bool hi = (rows_base >= N_);   // strip-uniform (N_ % 64 == 0)
  int rrow[4], prt[4];
#pragma unroll
  for (int j = 0; j < 4; ++j) {
    rrow[j] = rows_base + kg * 4 + j;
    prt[j]  = hi ? (rrow[j] - N_) : (rrow[j] + N_);
  }

  float accPv[4] = {0.f, 0.f, 0.f, 0.f};
  float accSv[4] = {0.f, 0.f, 0.f, 0.f};

  for (int ct = 0; ct < NT; ++ct) {
    const int c = cb0 + ct * 16 + lr;
    const short* bp = zs + (size_t)c * DFEAT + kg * 8;
    bf16x8 b[4];
#pragma unroll
    for (int kk = 0; kk < 4; ++kk)
      b[kk] = *(const bf16x8*)(bp + kk * 32);

    // two independent MFMA chains (halve matrix-pipe dependency depth)
    f32x4 acc0 = {0.f, 0.f, 0.f, 0.f};
    f32x4 acc1 = {0.f, 0.f, 0.f, 0.f};
    acc0 = __builtin_amdgcn_mfma_f32_16x16x32_bf16(a[0], b[0], acc0, 0, 0, 0);
    acc1 = __builtin_amdgcn_mfma_f32_16x16x32_bf16(a[1], b[1], acc1, 0, 0, 0);
    acc0 = __builtin_amdgcn_mfma_f32_16x16x32_bf16(a[2], b[2], acc0, 0, 0, 0);
    acc1 = __builtin_amdgcn_mfma_f32_16x16x32_bf16(a[3], b[3], acc1, 0, 0, 0);

#pragma unroll
    for (int j = 0; j < 4; ++j) {
      float e = __expf(SCALE * (acc0[j] + acc1[j]));
      const bool excl = (c == rrow[j]) || (c == prt[j]);  // diag + partner/q
      e = excl ? 0.0f : e;
      if (hi) {
        const bool toP = (c < prt[j]);                    // prt = q = r - N
        accPv[j] += toP ? e : 0.0f;
        accSv[j] += toP ? 0.0f : e;
      } else {
        accSv[j] += e;
      }
    }
  }

  // reduce across the 16 lanes sharing each row group, one atomic per row
#pragma unroll
  for (int j = 0; j < 4; ++j) {
    float pv = accPv[j], sv = accSv[j];
#pragma unroll
    for (int m = 1; m < 16; m <<= 1) {
      pv += __shfl_xor(pv, m);
      sv += __shfl_xor(sv, m);
    }
    if (lr == 0) {
      atomicAdd(&accS[rrow[j]], sv);
      if (hi) atomicAdd(&accP[rrow[j] - N_], pv);
    }
  }
}

// ---------------------------------------------------------------------------
// Kernel 3: finalize — reads only accS[4096], accP[2048], dvec[2048] (32 KB).
//   row i<N:        log(2*E[i] + S[i]) - d[i]
//   row N+i, i<N-1: log(E[i] + S[N+i] + accP[i+1]) - d[i]
//   row 2N-1:       log(E[N-1] + S[2N-1] + sum_j E[j]) - d[N-1]
// ---------------------------------------------------------------------------
__global__ __launch_bounds__(1024) void k_final(const float* __restrict__ dvec,
                                                const float* __restrict__ accS,
                                                const float* __restrict__ accP,
                                                float* __restrict__ out) {
  __shared__ float Elds[N_];
  __shared__ float red[16];
  const int tid = threadIdx.x;
  float dpart = 0.f;
  for (int i = tid; i < N_; i += 1024) {
    float E = __expf(dvec[i]);
    Elds[i] = E;
    dpart += E;
  }
#pragma unroll
  for (int m = 1; m < 64; m <<= 1) dpart += __shfl_xor(dpart, m);
  const int w = tid >> 6, l = tid & 63;
  if (l == 0) red[w] = dpart;
  __syncthreads();
  float Dsum = 0.f;
#pragma unroll
  for (int k = 0; k < 16; ++k) Dsum += red[k];
  __syncthreads();  // before reusing red[]

  float part = 0.f;
  for (int r = tid; r < TWO_N; r += 1024) {
    float S = accS[r];
    float t;
    if (r < N_) {
      t = logf(2.0f * Elds[r] + S) - dvec[r];
    } else {
      const int i = r - N_;
      const float extra = (i < N_ - 1) ? accP[i + 1] : Dsum;
      t = logf(Elds[i] + S + extra) - dvec[i];
    }
    part += t;
  }
#pragma unroll
  for (int m = 1; m < 64; m <<= 1) part += __shfl_xor(part, m);
  if (l == 0) red[w] = part;
  __syncthreads();
  if (tid == 0) {
    float tot = 0.f;
#pragma unroll
    for (int k = 0; k < 16; ++k) tot += red[k];
    out[0] = tot / (float)TWO_N;
  }
}

// ---------------------------------------------------------------------------
extern "C" void kernel_launch(void* const* d_in, const int* in_sizes, int n_in,
                              void* d_out, int out_size, void* d_ws, size_t ws_size,
                              hipStream_t stream) {
  const float* a  = (const float*)d_in[0];
  const float* p  = (const float*)d_in[1];
  const float* ng = (const float*)d_in[2];

  char* ws = (char*)d_ws;
  __hip_bfloat16* zn16 = (__hip_bfloat16*)ws;                    // 1 MB
  float* dvec = (float*)(ws + (size_t)TWO_N * DFEAT * 2);        // 16 KB slot
  float* accS = dvec + TWO_N;                                    // 16 KB
  float* accP = accS + TWO_N;                                    // 8 KB

  k_prep<<<TWO_N / 4, 256, 0, stream>>>(a, p, ng, zn16, dvec, accS, accP);
  k_simsum<<<dim3(GRID_X, CCHUNKS), 256, 0, stream>>>(zn16, accS, accP);
  k_final<<<1, 1024, 0, stream>>>(dvec, accS, accP, (float*)d_out);
}

// Round 6
// 47.504 us; speedup vs baseline: 1.1296x; 1.1296x over previous
//
#include <hip/hip_runtime.h>
#include <hip/hip_bf16.h>

#define N_      2048
#define TWO_N   4096
#define DFEAT   128
#define SCALE   2.0f                   // 1 / TEMPERATURE
#define CCHUNKS 32                     // column chunks in k_simsum
#define CCOLS   (TWO_N / CCHUNKS)      // 128
#define NT      (CCOLS / 16)           // 8 column-tiles per chunk
#define GRID_X  (TWO_N / 64)           // 64 row strips

typedef __attribute__((ext_vector_type(8))) short bf16x8;
typedef __attribute__((ext_vector_type(4))) float f32x4;

// ---------------------------------------------------------------------------
// Kernel 1 (fused prep), 1024 blocks x 256 thr (4 waves = 4 rows per block):
//   row < N : normalize anchor row -> zn16[row], AND dvec[row] = 2*cos(a,neg)
//   row >= N: normalize pos row   -> zn16[row]
//   Also zero-inits the atomic accumulators accS[4096] / accP[2048].
// ---------------------------------------------------------------------------
__global__ __launch_bounds__(256) void k_prep(const float* __restrict__ a,
                                              const float* __restrict__ p,
                                              const float* __restrict__ ng,
                                              __hip_bfloat16* __restrict__ zn16,
                                              float* __restrict__ dvec,
                                              float* __restrict__ accS,
                                              float* __restrict__ accP) {
  const int wave = threadIdx.x >> 6;
  const int lane = threadIdx.x & 63;
  const int row  = blockIdx.x * 4 + wave;   // 0..4095

  // zero atomic accumulators: 4 accS + 2 accP entries per block
  if (threadIdx.x < 4)        accS[blockIdx.x * 4 + threadIdx.x] = 0.0f;
  else if (threadIdx.x < 6)   accP[blockIdx.x * 2 + threadIdx.x - 4] = 0.0f;

  if (row < N_) {
    float2 u = ((const float2*)(a  + (size_t)row * DFEAT))[lane];
    float2 w = ((const float2*)(ng + (size_t)row * DFEAT))[lane];
    float saa = u.x * u.x + u.y * u.y;
    float snn = w.x * w.x + w.y * w.y;
    float san = u.x * w.x + u.y * w.y;
#pragma unroll
    for (int m = 1; m < 64; m <<= 1) {
      saa += __shfl_xor(saa, m);
      snn += __shfl_xor(snn, m);
      san += __shfl_xor(san, m);
    }
    float na = fmaxf(sqrtf(saa), 1e-8f);
    float rn = 1.0f / na;
    __hip_bfloat162 h;
    h.x = __float2bfloat16(u.x * rn);
    h.y = __float2bfloat16(u.y * rn);
    ((__hip_bfloat162*)zn16)[row * (DFEAT / 2) + lane] = h;
    if (lane == 0)
      dvec[row] = SCALE * san / (na * fmaxf(sqrtf(snn), 1e-8f));
  } else {
    float2 v = ((const float2*)(p + (size_t)(row - N_) * DFEAT))[lane];
    float ss = v.x * v.x + v.y * v.y;
#pragma unroll
    for (int m = 1; m < 64; m <<= 1) ss += __shfl_xor(ss, m);
    float rn = 1.0f / fmaxf(sqrtf(ss), 1e-8f);
    __hip_bfloat162 h;
    h.x = __float2bfloat16(v.x * rn);
    h.y = __float2bfloat16(v.y * rn);
    ((__hip_bfloat162*)zn16)[row * (DFEAT / 2) + lane] = h;
  }
}

// ---------------------------------------------------------------------------
// Kernel 2: fused G = zn@zn^T /T, exp, masked row-segment sums -> atomics.
//   grid = (64 row strips, 32 col chunks) = 2048 blocks, 256 thr (4 waves).
//   NO forced min-occupancy: plain launch_bounds(256) -> ~44 VGPR, no spill
//   (R5's (256,8) forced VGPR=32 and spilled 23.5 MB of scratch per dispatch).
//   44 VGPR <= 64 still allows 8 waves/SIMD -> 8 blocks/CU, full occupancy.
// ---------------------------------------------------------------------------
__global__ __launch_bounds__(256) void k_simsum(const __hip_bfloat16* __restrict__ zn16,
                                                float* __restrict__ accS,
                                                float* __restrict__ accP) {
  const int wave = threadIdx.x >> 6;
  const int lane = threadIdx.x & 63;
  const int lr   = lane & 15;   // A-row / B-col within tile
  const int kg   = lane >> 4;   // k-group
  const int rows_base = blockIdx.x * 64 + wave * 16;
  const int cb0 = blockIdx.y * CCOLS;
  const short* zs = (const short*)zn16;

  // A fragments for this wave's 16 rows, all K=128 (4 subtiles), in regs
  bf16x8 a[4];
#pragma unroll
  for (int kk = 0; kk < 4; ++kk)
    a[kk] = *(const bf16x8*)(zs + (size_t)(rows_base + lr) * DFEAT + kk * 32 + kg * 8);

  const bool hi = (rows_base >= N_);   // strip-uniform (N_ % 64 == 0)
  int rrow[4], prt[4];
#pragma unroll
  for (int j = 0; j < 4; ++j) {
    rrow[j] = rows_base + kg * 4 + j;
    prt[j]  = hi ? (rrow[j] - N_) : (rrow[j] + N_);
  }

  float accPv[4] = {0.f, 0.f, 0.f, 0.f};
  float accSv[4] = {0.f, 0.f, 0.f, 0.f};

  for (int ct = 0; ct < NT; ++ct) {
    const int c = cb0 + ct * 16 + lr;
    const short* bp = zs + (size_t)c * DFEAT + kg * 8;
    bf16x8 b[4];
#pragma unroll
    for (int kk = 0; kk < 4; ++kk)
      b[kk] = *(const bf16x8*)(bp + kk * 32);

    // two independent MFMA chains (halve matrix-pipe dependency depth)
    f32x4 acc0 = {0.f, 0.f, 0.f, 0.f};
    f32x4 acc1 = {0.f, 0.f, 0.f, 0.f};
    acc0 = __builtin_amdgcn_mfma_f32_16x16x32_bf16(a[0], b[0], acc0, 0, 0, 0);
    acc1 = __builtin_amdgcn_mfma_f32_16x16x32_bf16(a[1], b[1], acc1, 0, 0, 0);
    acc0 = __builtin_amdgcn_mfma_f32_16x16x32_bf16(a[2], b[2], acc0, 0, 0, 0);
    acc1 = __builtin_amdgcn_mfma_f32_16x16x32_bf16(a[3], b[3], acc1, 0, 0, 0);

#pragma unroll
    for (int j = 0; j < 4; ++j) {
      float e = __expf(SCALE * (acc0[j] + acc1[j]));
      const bool excl = (c == rrow[j]) || (c == prt[j]);  // diag + partner/q
      e = excl ? 0.0f : e;
      if (hi) {
        const bool toP = (c < prt[j]);                    // prt = q = r - N
        accPv[j] += toP ? e : 0.0f;
        accSv[j] += toP ? 0.0f : e;
      } else {
        accSv[j] += e;
      }
    }
  }

  // reduce across the 16 lanes sharing each row group, one atomic per row
#pragma unroll
  for (int j = 0; j < 4; ++j) {
    float pv = accPv[j], sv = accSv[j];
#pragma unroll
    for (int m = 1; m < 16; m <<= 1) {
      pv += __shfl_xor(pv, m);
      sv += __shfl_xor(sv, m);
    }
    if (lr == 0) {
      atomicAdd(&accS[rrow[j]], sv);
      if (hi) atomicAdd(&accP[rrow[j] - N_], pv);
    }
  }
}

// ---------------------------------------------------------------------------
// Kernel 3: finalize — reads only accS[4096], accP[2048], dvec[2048] (32 KB).
//   row i<N:        log(2*E[i] + S[i]) - d[i]
//   row N+i, i<N-1: log(E[i] + S[N+i] + accP[i+1]) - d[i]
//   row 2N-1:       log(E[N-1] + S[2N-1] + sum_j E[j]) - d[N-1]
// ---------------------------------------------------------------------------
__global__ __launch_bounds__(1024) void k_final(const float* __restrict__ dvec,
                                                const float* __restrict__ accS,
                                                const float* __restrict__ accP,
                                                float* __restrict__ out) {
  __shared__ float Elds[N_];
  __shared__ float red[16];
  const int tid = threadIdx.x;
  float dpart = 0.f;
  for (int i = tid; i < N_; i += 1024) {
    float E = __expf(dvec[i]);
    Elds[i] = E;
    dpart += E;
  }
#pragma unroll
  for (int m = 1; m < 64; m <<= 1) dpart += __shfl_xor(dpart, m);
  const int w = tid >> 6, l = tid & 63;
  if (l == 0) red[w] = dpart;
  __syncthreads();
  float Dsum = 0.f;
#pragma unroll
  for (int k = 0; k < 16; ++k) Dsum += red[k];
  __syncthreads();  // before reusing red[]

  float part = 0.f;
  for (int r = tid; r < TWO_N; r += 1024) {
    float S = accS[r];
    float t;
    if (r < N_) {
      t = logf(2.0f * Elds[r] + S) - dvec[r];
    } else {
      const int i = r - N_;
      const float extra = (i < N_ - 1) ? accP[i + 1] : Dsum;
      t = logf(Elds[i] + S + extra) - dvec[i];
    }
    part += t;
  }
#pragma unroll
  for (int m = 1; m < 64; m <<= 1) part += __shfl_xor(part, m);
  if (l == 0) red[w] = part;
  __syncthreads();
  if (tid == 0) {
    float tot = 0.f;
#pragma unroll
    for (int k = 0; k < 16; ++k) tot += red[k];
    out[0] = tot / (float)TWO_N;
  }
}

// ---------------------------------------------------------------------------
extern "C" void kernel_launch(void* const* d_in, const int* in_sizes, int n_in,
                              void* d_out, int out_size, void* d_ws, size_t ws_size,
                              hipStream_t stream) {
  const float* a  = (const float*)d_in[0];
  const float* p  = (const float*)d_in[1];
  const float* ng = (const float*)d_in[2];

  char* ws = (char*)d_ws;
  __hip_bfloat16* zn16 = (__hip_bfloat16*)ws;                    // 1 MB
  float* dvec = (float*)(ws + (size_t)TWO_N * DFEAT * 2);        // 16 KB slot
  float* accS = dvec + TWO_N;                                    // 16 KB
  float* accP = accS + TWO_N;                                    // 8 KB

  k_prep<<<TWO_N / 4, 256, 0, stream>>>(a, p, ng, zn16, dvec, accS, accP);
  k_simsum<<<dim3(GRID_X, CCHUNKS), 256, 0, stream>>>(zn16, accS, accP);
  k_final<<<1, 1024, 0, stream>>>(dvec, accS, accP, (float*)d_out);
}

// Round 7
// 26.787 us; speedup vs baseline: 2.0033x; 1.7734x over previous
//
#include <hip/hip_runtime.h>
#include <hip/hip_bf16.h>

#define N_      2048
#define TWO_N   4096
#define DFEAT   128
#define SCALE   2.0f                   // 1 / TEMPERATURE
#define BROWS   128                    // rows per block  (4 waves x 32)
#define BCOLS   128                    // cols per block (LDS-staged panel)
#define NT      (BCOLS / 16)           // 8 column-tiles per panel
#define LDSTR   136                    // shorts per col in LDS (128 + 8 pad = 272 B)

typedef __attribute__((ext_vector_type(8))) short bf16x8;
typedef __attribute__((ext_vector_type(4))) float f32x4;

// ---------------------------------------------------------------------------
// Kernel 1 (fused prep), 1024 blocks x 256 thr (4 waves = 4 rows per block):
//   row < N : normalize anchor row -> zn16[row], AND dvec[row] = 2*cos(a,neg)
//   row >= N: normalize pos row   -> zn16[row]
//   Also zero-inits the atomic accumulators accS[4096] / accP[2048].
// ---------------------------------------------------------------------------
__global__ __launch_bounds__(256) void k_prep(const float* __restrict__ a,
                                              const float* __restrict__ p,
                                              const float* __restrict__ ng,
                                              __hip_bfloat16* __restrict__ zn16,
                                              float* __restrict__ dvec,
                                              float* __restrict__ accS,
                                              float* __restrict__ accP) {
  const int wave = threadIdx.x >> 6;
  const int lane = threadIdx.x & 63;
  const int row  = blockIdx.x * 4 + wave;   // 0..4095

  // zero atomic accumulators: 4 accS + 2 accP entries per block
  if (threadIdx.x < 4)        accS[blockIdx.x * 4 + threadIdx.x] = 0.0f;
  else if (threadIdx.x < 6)   accP[blockIdx.x * 2 + threadIdx.x - 4] = 0.0f;

  if (row < N_) {
    float2 u = ((const float2*)(a  + (size_t)row * DFEAT))[lane];
    float2 w = ((const float2*)(ng + (size_t)row * DFEAT))[lane];
    float saa = u.x * u.x + u.y * u.y;
    float snn = w.x * w.x + w.y * w.y;
    float san = u.x * w.x + u.y * w.y;
#pragma unroll
    for (int m = 1; m < 64; m <<= 1) {
      saa += __shfl_xor(saa, m);
      snn += __shfl_xor(snn, m);
      san += __shfl_xor(san, m);
    }
    float na = fmaxf(sqrtf(saa), 1e-8f);
    float rn = 1.0f / na;
    __hip_bfloat162 h;
    h.x = __float2bfloat16(u.x * rn);
    h.y = __float2bfloat16(u.y * rn);
    ((__hip_bfloat162*)zn16)[row * (DFEAT / 2) + lane] = h;
    if (lane == 0)
      dvec[row] = SCALE * san / (na * fmaxf(sqrtf(snn), 1e-8f));
  } else {
    float2 v = ((const float2*)(p + (size_t)(row - N_) * DFEAT))[lane];
    float ss = v.x * v.x + v.y * v.y;
#pragma unroll
    for (int m = 1; m < 64; m <<= 1) ss += __shfl_xor(ss, m);
    float rn = 1.0f / fmaxf(sqrtf(ss), 1e-8f);
    __hip_bfloat162 h;
    h.x = __float2bfloat16(v.x * rn);
    h.y = __float2bfloat16(v.y * rn);
    ((__hip_bfloat162*)zn16)[row * (DFEAT / 2) + lane] = h;
  }
}

// ---------------------------------------------------------------------------
// Kernel 2: fused G = zn@zn^T /T, exp, masked row-segment sums -> atomics.
//   grid = (32 row strips x 32 col chunks) = 1024 blocks, 256 thr (4 waves).
//   Block stages its 128-col B-panel in LDS ONCE (dense coalesced 16B/lane
//   global loads -> conflict-free padded-stride ds_write_b128), then each
//   wave computes TWO 16-row tiles (32 rows) x 128 cols via ds_read_b128
//   (each B fragment feeds 2 independent MFMA chains).
//   No per-iteration barriers; panel loaded once. Fixes R6's 16-segment
//   global gather that throttled the TA/L1 path.
// ---------------------------------------------------------------------------
__global__ __launch_bounds__(256) void k_simsum(const __hip_bfloat16* __restrict__ zn16,
                                                float* __restrict__ accS,
                                                float* __restrict__ accP) {
  __shared__ short Bp[BCOLS * LDSTR];   // 34816 B

  const int wave = threadIdx.x >> 6;
  const int lane = threadIdx.x & 63;
  const int lr   = lane & 15;   // A-row / B-col within tile
  const int kg   = lane >> 4;   // k-group
  const int rows_base = blockIdx.x * BROWS + wave * 32;
  const int cb0 = blockIdx.y * BCOLS;
  const short* zs = (const short*)zn16;

  // A fragments: two 16-row tiles (gathered once per kernel)
  bf16x8 a0[4], a1[4];
#pragma unroll
  for (int kk = 0; kk < 4; ++kk) {
    a0[kk] = *(const bf16x8*)(zs + (size_t)(rows_base + lr) * DFEAT + kk * 32 + kg * 8);
    a1[kk] = *(const bf16x8*)(zs + (size_t)(rows_base + 16 + lr) * DFEAT + kk * 32 + kg * 8);
  }

  // stage B panel: 128 cols x 256 B = 2048 16-B chunks, 256 thr -> 8 passes.
  // chunk g: col = g>>4, q = g&15. Global: dense coalesced. LDS: 272-B stride.
#pragma unroll
  for (int it = 0; it < 8; ++it) {
    const int g   = it * 256 + threadIdx.x;
    const int col = g >> 4;
    const int q   = g & 15;
    bf16x8 v = *(const bf16x8*)(zs + (size_t)(cb0 + col) * DFEAT + q * 8);
    *(bf16x8*)(&Bp[col * LDSTR + q * 8]) = v;
  }
  __syncthreads();

  const bool hi = (rows_base >= N_);   // block-uniform (BROWS=128 divides N_)
  int rrow[2][4], prt[2][4];
#pragma unroll
  for (int t = 0; t < 2; ++t)
#pragma unroll
    for (int j = 0; j < 4; ++j) {
      rrow[t][j] = rows_base + t * 16 + kg * 4 + j;
      prt[t][j]  = hi ? (rrow[t][j] - N_) : (rrow[t][j] + N_);
    }

  float accPv[2][4] = {{0.f,0.f,0.f,0.f},{0.f,0.f,0.f,0.f}};
  float accSv[2][4] = {{0.f,0.f,0.f,0.f},{0.f,0.f,0.f,0.f}};

#pragma unroll 1
  for (int ct = 0; ct < NT; ++ct) {
    bf16x8 b[4];
#pragma unroll
    for (int kk = 0; kk < 4; ++kk)
      b[kk] = *(const bf16x8*)(&Bp[(ct * 16 + lr) * LDSTR + kk * 32 + kg * 8]);

    // two independent MFMA chains (one per row-tile), B shared
    f32x4 acc0 = {0.f, 0.f, 0.f, 0.f};
    f32x4 acc1 = {0.f, 0.f, 0.f, 0.f};
#pragma unroll
    for (int kk = 0; kk < 4; ++kk) {
      acc0 = __builtin_amdgcn_mfma_f32_16x16x32_bf16(a0[kk], b[kk], acc0, 0, 0, 0);
      acc1 = __builtin_amdgcn_mfma_f32_16x16x32_bf16(a1[kk], b[kk], acc1, 0, 0, 0);
    }

    const int c = cb0 + ct * 16 + lr;
#pragma unroll
    for (int j = 0; j < 4; ++j) {
      {
        float e = __expf(SCALE * acc0[j]);
        const bool excl = (c == rrow[0][j]) || (c == prt[0][j]);
        e = excl ? 0.0f : e;
        if (hi) {
          const bool toP = (c < prt[0][j]);
          accPv[0][j] += toP ? e : 0.0f;
          accSv[0][j] += toP ? 0.0f : e;
        } else {
          accSv[0][j] += e;
        }
      }
      {
        float e = __expf(SCALE * acc1[j]);
        const bool excl = (c == rrow[1][j]) || (c == prt[1][j]);
        e = excl ? 0.0f : e;
        if (hi) {
          const bool toP = (c < prt[1][j]);
          accPv[1][j] += toP ? e : 0.0f;
          accSv[1][j] += toP ? 0.0f : e;
        } else {
          accSv[1][j] += e;
        }
      }
    }
  }

  // reduce across the 16 lanes sharing each row group, one atomic per row
#pragma unroll
  for (int t = 0; t < 2; ++t)
#pragma unroll
    for (int j = 0; j < 4; ++j) {
      float pv = accPv[t][j], sv = accSv[t][j];
#pragma unroll
      for (int m = 1; m < 16; m <<= 1) {
        sv += __shfl_xor(sv, m);
        if (hi) pv += __shfl_xor(pv, m);
      }
      if (lr == 0) {
        atomicAdd(&accS[rrow[t][j]], sv);
        if (hi) atomicAdd(&accP[rrow[t][j] - N_], pv);
      }
    }
}

// ---------------------------------------------------------------------------
// Kernel 3: finalize — reads only accS[4096], accP[2048], dvec[2048] (32 KB).
//   row i<N:        log(2*E[i] + S[i]) - d[i]
//   row N+i, i<N-1: log(E[i] + S[N+i] + accP[i+1]) - d[i]
//   row 2N-1:       log(E[N-1] + S[2N-1] + sum_j E[j]) - d[N-1]
// ---------------------------------------------------------------------------
__global__ __launch_bounds__(1024) void k_final(const float* __restrict__ dvec,
                                                const float* __restrict__ accS,
                                                const float* __restrict__ accP,
                                                float* __restrict__ out) {
  __shared__ float Elds[N_];
  __shared__ float red[16];
  const int tid = threadIdx.x;
  float dpart = 0.f;
  for (int i = tid; i < N_; i += 1024) {
    float E = __expf(dvec[i]);
    Elds[i] = E;
    dpart += E;
  }
#pragma unroll
  for (int m = 1; m < 64; m <<= 1) dpart += __shfl_xor(dpart, m);
  const int w = tid >> 6, l = tid & 63;
  if (l == 0) red[w] = dpart;
  __syncthreads();
  float Dsum = 0.f;
#pragma unroll
  for (int k = 0; k < 16; ++k) Dsum += red[k];
  __syncthreads();  // before reusing red[]

  float part = 0.f;
  for (int r = tid; r < TWO_N; r += 1024) {
    float S = accS[r];
    float t;
    if (r < N_) {
      t = logf(2.0f * Elds[r] + S) - dvec[r];
    } else {
      const int i = r - N_;
      const float extra = (i < N_ - 1) ? accP[i + 1] : Dsum;
      t = logf(Elds[i] + S + extra) - dvec[i];
    }
    part += t;
  }
#pragma unroll
  for (int m = 1; m < 64; m <<= 1) part += __shfl_xor(part, m);
  if (l == 0) red[w] = part;
  __syncthreads();
  if (tid == 0) {
    float tot = 0.f;
#pragma unroll
    for (int k = 0; k < 16; ++k) tot += red[k];
    out[0] = tot / (float)TWO_N;
  }
}

// ---------------------------------------------------------------------------
extern "C" void kernel_launch(void* const* d_in, const int* in_sizes, int n_in,
                              void* d_out, int out_size, void* d_ws, size_t ws_size,
                              hipStream_t stream) {
  const float* a  = (const float*)d_in[0];
  const float* p  = (const float*)d_in[1];
  const float* ng = (const float*)d_in[2];

  char* ws = (char*)d_ws;
  __hip_bfloat16* zn16 = (__hip_bfloat16*)ws;                    // 1 MB
  float* dvec = (float*)(ws + (size_t)TWO_N * DFEAT * 2);        // 16 KB slot
  float* accS = dvec + TWO_N;                                    // 16 KB
  float* accP = accS + TWO_N;                                    // 8 KB

  k_prep<<<TWO_N / 4, 256, 0, stream>>>(a, p, ng, zn16, dvec, accS, accP);
  k_simsum<<<dim3(TWO_N / BROWS, TWO_N / BCOLS), 256, 0, stream>>>(zn16, accS, accP);
  k_final<<<1, 1024, 0, stream>>>(dvec, accS, accP, (float*)d_out);
}